// Round 1
// baseline (450.539 us; speedup 1.0000x reference)
//
#include <hip/hip_runtime.h>
#include <hip/hip_bf16.h>
#include <stdint.h>

#define NDIM 4096

typedef __attribute__((ext_vector_type(8))) __bf16 bf16x8;
typedef __attribute__((ext_vector_type(4))) float f32x4;

__device__ inline void g2lds16(const void* g, void* l) {
  __builtin_amdgcn_global_load_lds(
      (const __attribute__((address_space(1))) void*)g,
      (__attribute__((address_space(3))) void*)l, 16, 0, 0);
}

__device__ inline unsigned short f2bf(float f) {
  union { float f; uint32_t u; } c; c.f = f;
  uint32_t u = c.u;
  uint32_t r = ((u >> 16) & 1u) + 0x7FFFu;
  return (unsigned short)((u + r) >> 16);
}

// ---------------- fp32 -> bf16 convert (vectorized) ----------------
__global__ __launch_bounds__(256) void convert_kernel(const float* __restrict__ in,
                                                      ushort* __restrict__ out) {
  int idx = blockIdx.x * 256 + threadIdx.x;
  float4 v = ((const float4*)in)[idx];
  ushort4 o;
  o.x = f2bf(v.x); o.y = f2bf(v.y); o.z = f2bf(v.z); o.w = f2bf(v.w);
  ((ushort4*)out)[idx] = o;
}

// ---------------- big GEMM: q = A @ B^T + bias  (bf16 MFMA, m97 structure) ----
// A = data_q [4096,4096] bf16 row-major, B = W_q [4096,4096] bf16 row-major.
// q[i,j] = sum_k A[i,k]*B[j,k] + bias[j], fp32 out.
#define BM 128
#define BN 128
#define BK 64

__global__ __launch_bounds__(256) void gemm_q_kernel(const ushort* __restrict__ Abf,
                                                     const ushort* __restrict__ Bbf,
                                                     const float* __restrict__ bias,
                                                     float* __restrict__ q) {
  __shared__ __align__(16) ushort As[BM * BK];  // [128][64]
  __shared__ __align__(16) ushort Bs[BN * BK];  // [128][64]

  const int tid = threadIdx.x;
  // XCD-aware swizzle (nwg = 1024, divisible by 8)
  int wg = blockIdx.x;
  int cpx = gridDim.x >> 3;
  int swz = (wg & 7) * cpx + (wg >> 3);
  const int bi = swz >> 5;  // 32 tiles per dim
  const int bj = swz & 31;
  const int i0 = bi * BM, j0 = bj * BN;

  const int lane = tid & 63;
  const int wave = tid >> 6;           // 4 waves, 2x2
  const int wr = wave >> 1, wc = wave & 1;
  const int l15 = lane & 15, lg = lane >> 4;

  // staging map: thread covers 16B; each 4KB issue = 32 rows of 128B
  const int srow = tid >> 3;           // 0..31
  const int scol = (tid & 7) * 8;      // bf16 elem col, 0..56

  f32x4 acc[4][4] = {};

  for (int k0 = 0; k0 < NDIM; k0 += BK) {
    __syncthreads();  // previous tile's LDS reads done
#pragma unroll
    for (int p = 0; p < 4; ++p) {
      const int r = p * 32 + srow;
      g2lds16(Abf + (size_t)(i0 + r) * NDIM + k0 + scol, &As[r * BK + scol]);
      g2lds16(Bbf + (size_t)(j0 + r) * NDIM + k0 + scol, &Bs[r * BK + scol]);
    }
    asm volatile("s_waitcnt vmcnt(0)" ::: "memory");
    __syncthreads();

#pragma unroll
    for (int kk = 0; kk < BK / 32; ++kk) {
      bf16x8 af[4], bfr[4];
#pragma unroll
      for (int m = 0; m < 4; ++m)
        af[m] = *(const bf16x8*)&As[(wr * 64 + m * 16 + l15) * BK + kk * 32 + lg * 8];
#pragma unroll
      for (int n = 0; n < 4; ++n)
        bfr[n] = *(const bf16x8*)&Bs[(wc * 64 + n * 16 + l15) * BK + kk * 32 + lg * 8];
#pragma unroll
      for (int m = 0; m < 4; ++m)
#pragma unroll
        for (int n = 0; n < 4; ++n)
          acc[m][n] = __builtin_amdgcn_mfma_f32_16x16x32_bf16(af[m], bfr[n], acc[m][n], 0, 0, 0);
    }
  }

  // epilogue: C[row=(lg*4+r), col=l15] per fragment, + bias[col]
#pragma unroll
  for (int m = 0; m < 4; ++m) {
    const int row = i0 + wr * 64 + m * 16 + lg * 4;
#pragma unroll
    for (int n = 0; n < 4; ++n) {
      const int col = j0 + wc * 64 + n * 16 + l15;
      const float bv = bias[col];
#pragma unroll
      for (int r = 0; r < 4; ++r)
        q[(size_t)(row + r) * NDIM + col] = acc[m][n][r] + bv;
    }
  }
}

// ---------------- k = data_k @ W_k^T + b_k  -> k_out[j][m], [6][4096] -------
__global__ __launch_bounds__(256) void gemv_k_kernel(const float* __restrict__ data_k,
                                                     const float* __restrict__ W_k,
                                                     const float* __restrict__ b_k,
                                                     float* __restrict__ k_out) {
  const int wave = threadIdx.x >> 6, lane = threadIdx.x & 63;
  const int m = blockIdx.x * 4 + wave;  // grid 1024 -> m in [0,4096)
  const float4* W = (const float4*)(W_k + (size_t)m * NDIM);
  const float4* D = (const float4*)data_k;
  float acc[6] = {0.f, 0.f, 0.f, 0.f, 0.f, 0.f};
  for (int it = lane; it < NDIM / 4; it += 64) {
    float4 w = W[it];
#pragma unroll
    for (int j = 0; j < 6; ++j) {
      float4 d = D[j * (NDIM / 4) + it];
      acc[j] += w.x * d.x + w.y * d.y + w.z * d.z + w.w * d.w;
    }
  }
#pragma unroll
  for (int j = 0; j < 6; ++j)
#pragma unroll
    for (int off = 1; off < 64; off <<= 1) acc[j] += __shfl_xor(acc[j], off);
  if (lane == 0) {
    const float bv = b_k[m];
#pragma unroll
    for (int j = 0; j < 6; ++j) k_out[j * NDIM + m] = acc[j] + bv;
  }
}

// ---------------- new_q^T partials: newq_t[j][m] += sum_n q[n,m]*W_lin[j,n] --
__global__ __launch_bounds__(256) void newq_kernel(const float* __restrict__ q,
                                                   const float* __restrict__ W_lin,
                                                   float* __restrict__ newq_t) {
  const int m = blockIdx.x * 256 + threadIdx.x;  // grid.x = 16
  const int n0 = blockIdx.y * 128;               // grid.y = 32
  float acc[6] = {0.f, 0.f, 0.f, 0.f, 0.f, 0.f};
  for (int n = n0; n < n0 + 128; ++n) {
    const float qv = q[(size_t)n * NDIM + m];
#pragma unroll
    for (int j = 0; j < 6; ++j) acc[j] += qv * W_lin[j * NDIM + n];
  }
#pragma unroll
  for (int j = 0; j < 6; ++j) atomicAdd(&newq_t[j * NDIM + m], acc[j]);
}

// ---------------- k_mod = relu6(k^2 + 2k + (newq_t + b_lin)*(1+|k|)) --------
__global__ __launch_bounds__(256) void kmod_kernel(const float* __restrict__ k_in,
                                                   const float* __restrict__ newq_t,
                                                   const float* __restrict__ b_lin,
                                                   float* __restrict__ k_mod) {
  const int idx = blockIdx.x * 256 + threadIdx.x;  // 0..24575
  const int j = idx >> 12;
  const float kv = k_in[idx];
  const float ctx = newq_t[idx] + b_lin[j];
  float v = kv * kv + 2.f * kv + ctx * (1.f + fabsf(kv));
  v = fminf(fmaxf(v, 0.f), 6.f);
  k_mod[idx] = v;
}

// ---------------- out[n][j] = (sum_m q[n,m]*k_mod[j,m]) / 64 ----------------
__global__ __launch_bounds__(256) void dot_kernel(const float* __restrict__ q,
                                                  const float* __restrict__ k_mod,
                                                  float* __restrict__ out) {
  const int wave = threadIdx.x >> 6, lane = threadIdx.x & 63;
  const int n = blockIdx.x * 4 + wave;  // grid 1024
  const float4* Q = (const float4*)(q + (size_t)n * NDIM);
  const float4* KM = (const float4*)k_mod;
  float acc[6] = {0.f, 0.f, 0.f, 0.f, 0.f, 0.f};
  for (int it = lane; it < NDIM / 4; it += 64) {
    float4 qv = Q[it];
#pragma unroll
    for (int j = 0; j < 6; ++j) {
      float4 km = KM[j * (NDIM / 4) + it];
      acc[j] += qv.x * km.x + qv.y * km.y + qv.z * km.z + qv.w * km.w;
    }
  }
#pragma unroll
  for (int j = 0; j < 6; ++j)
#pragma unroll
    for (int off = 1; off < 64; off <<= 1) acc[j] += __shfl_xor(acc[j], off);
  if (lane == 0) {
#pragma unroll
    for (int j = 0; j < 6; ++j) out[n * 6 + j] = acc[j] * 0.015625f;  // /sqrt(4096)
  }
}

extern "C" void kernel_launch(void* const* d_in, const int* in_sizes, int n_in,
                              void* d_out, int out_size, void* d_ws, size_t ws_size,
                              hipStream_t stream) {
  const float* data_q = (const float*)d_in[0];
  const float* data_k = (const float*)d_in[1];
  const float* W_q    = (const float*)d_in[2];
  const float* b_q    = (const float*)d_in[3];
  const float* W_lin  = (const float*)d_in[4];
  const float* b_lin  = (const float*)d_in[5];
  const float* W_k    = (const float*)d_in[6];
  const float* b_k    = (const float*)d_in[7];
  float* out = (float*)d_out;

  char* ws = (char*)d_ws;
  ushort* Abf   = (ushort*)ws;                          // 32 MB
  ushort* Bbf   = (ushort*)(ws + ((size_t)32 << 20));   // 32 MB
  float*  q     = (float*)(ws + ((size_t)64 << 20));    // 64 MB
  float*  k_arr = (float*)(ws + ((size_t)128 << 20));   // 96 KB
  float*  newq  = k_arr + 6 * NDIM;                     // 96 KB
  float*  kmod  = newq + 6 * NDIM;                      // 96 KB

  hipMemsetAsync(newq, 0, 6 * NDIM * sizeof(float), stream);

  convert_kernel<<<16384, 256, 0, stream>>>(data_q, Abf);
  convert_kernel<<<16384, 256, 0, stream>>>(W_q, Bbf);
  gemm_q_kernel<<<1024, 256, 0, stream>>>(Abf, Bbf, b_q, q);
  gemv_k_kernel<<<1024, 256, 0, stream>>>(data_k, W_k, b_k, k_arr);
  newq_kernel<<<dim3(16, 32), 256, 0, stream>>>(q, W_lin, newq);
  kmod_kernel<<<96, 256, 0, stream>>>(k_arr, newq, b_lin, kmod);
  dot_kernel<<<1024, 256, 0, stream>>>(q, kmod, out);
}